// Round 11
// baseline (153.483 us; speedup 1.0000x reference)
//
#include <hip/hip_runtime.h>
#include <hip/hip_bf16.h>

// Problem constants (B=1 folded out)
constexpr int T = 8;     // frames
constexpr int C = 128;   // input channels
constexpr int N = 4096;  // H*W positions
constexpr int F = 64;    // feature dim

typedef __bf16 bf16x8 __attribute__((ext_vector_type(8)));
typedef __bf16 bf16x4 __attribute__((ext_vector_type(4)));
typedef __bf16 bf16x2 __attribute__((ext_vector_type(2)));
typedef float  f32x4  __attribute__((ext_vector_type(4)));
typedef float  f32x16 __attribute__((ext_vector_type(16)));

constexpr int KSPLIT = 4;
constexpr int XS = 136;   // proj X^T LDS stride (272B rows)
constexpr int KS = 72;    // attn K/G LDS stride (144B rows)

// ---------------------------------------------------------------------------
// Kernel 0: W1/W2/W3 (fp32 [F][C]) -> bf16 packed [3][F][C]. 96 blocks.
// (zero-out moved into proj_kernel's pj==0 blocks)
// ---------------------------------------------------------------------------
__global__ __launch_bounds__(256) void setup_kernel(
    const float* __restrict__ W1, const float* __restrict__ W2,
    const float* __restrict__ W3, __bf16* __restrict__ Wb)
{
    int i = blockIdx.x * 256 + threadIdx.x;   // 96*256 = 24576 = 3*F*C
    int p = i >> 13, r = i & 8191;
    const float* W = (p == 0) ? W1 : (p == 1) ? W2 : W3;
    Wb[i] = (__bf16)W[r];
}

// ---------------------------------------------------------------------------
// Kernel 1: projections, split by projection (R7/R8-verified) + fused zero.
// blockIdx.y = pj in {0:Q, 1:K, 2:G}; grid (512, 3). pj==0 blocks also zero
// their 16 KB slice of d_out (attn accumulates into it with atomics; kernel
// boundary orders zero before attn).
//   Q,K: D[m=f][n'=n] = W · X^T -> [n][F], b64 stores over f
//   G:   D[m=n][n'=f] = X^T · W3 -> [f][N], b64 stores over n
// ---------------------------------------------------------------------------
__global__ __launch_bounds__(256) void proj_kernel(
    const float* __restrict__ x1, const float* __restrict__ x2,
    const __bf16* __restrict__ Wb,
    const float* __restrict__ b1, const float* __restrict__ b2,
    const float* __restrict__ b3,
    __bf16* __restrict__ Qb, __bf16* __restrict__ Kb, __bf16* __restrict__ Gw,
    float* __restrict__ out)
{
    const int pj = blockIdx.y;        // 0=Q, 1=K, 2=G
    const int t  = blockIdx.x >> 6;
    const int nb = blockIdx.x & 63;
    const int n0 = nb * 64;

    __shared__ __bf16 Xt[64 * XS];
    const float* X = (pj == 1) ? x2 : x1;

    const int tid = threadIdx.x;

    // fused zero of d_out: 512 pj==0 blocks x 256 threads x 4 f32x4 = 8.4 MB
    if (pj == 0) {
        f32x4* o4 = (f32x4*)out;
        const int b0 = blockIdx.x * 1024 + tid;
#pragma unroll
        for (int k = 0; k < 4; ++k)
            o4[b0 + k * 256] = (f32x4){0.f, 0.f, 0.f, 0.f};
    }

    const int ng  = tid & 15;         // n-block: n = ng*4 + j
    const int cgi = tid >> 4;         // c-group: c = cgi*4 (+64 per pass)

#pragma unroll
    for (int pass = 0; pass < 2; ++pass) {
        const int c0 = cgi * 4 + pass * 64;
        const size_t base = ((size_t)t * C + c0) * (size_t)N + n0 + ng * 4;
        f32x4 v[4];
#pragma unroll
        for (int i = 0; i < 4; ++i) v[i] = *(const f32x4*)&X[base + (size_t)i * N];
#pragma unroll
        for (int j = 0; j < 4; ++j) {
            bf16x4 o;
#pragma unroll
            for (int i = 0; i < 4; ++i) o[i] = (__bf16)v[i][j];
            *(bf16x4*)&Xt[(ng * 4 + j) * XS + c0] = o;
        }
    }
    __syncthreads();

    const int wave = tid >> 6, lane = tid & 63;
    const int quad = lane >> 4, l16 = lane & 15;

    bf16x8 a[4];
#pragma unroll
    for (int cc = 0; cc < 4; ++cc)
        a[cc] = *(const bf16x8*)&Xt[(wave * 16 + l16) * XS + cc * 32 + quad * 8];

    const __bf16* W = Wb + (size_t)pj * F * C;

    if (pj < 2) {
        const float* bias = pj ? b2 : b1;
        __bf16*      O    = pj ? Kb : Qb;
        f32x4 acc[4];
#pragma unroll
        for (int ft = 0; ft < 4; ++ft) acc[ft] = (f32x4){0.f, 0.f, 0.f, 0.f};
#pragma unroll
        for (int cc = 0; cc < 4; ++cc)
#pragma unroll
            for (int ft = 0; ft < 4; ++ft) {
                bf16x8 wf = *(const bf16x8*)&W[(ft * 16 + l16) * C + cc * 32 + quad * 8];
                acc[ft] = __builtin_amdgcn_mfma_f32_16x16x32_bf16(wf, a[cc], acc[ft], 0, 0, 0);
            }
        const int n = n0 + wave * 16 + l16;
#pragma unroll
        for (int ft = 0; ft < 4; ++ft) {
            const int f0 = ft * 16 + quad * 4;
            f32x4 bv = *(const f32x4*)&bias[f0];
            bf16x4 o;
#pragma unroll
            for (int r = 0; r < 4; ++r) o[r] = (__bf16)(acc[ft][r] + bv[r]);
            *(bf16x4*)&O[((size_t)t * N + n) * F + f0] = o;
        }
    } else {
        f32x4 acc[4];
#pragma unroll
        for (int ft = 0; ft < 4; ++ft) acc[ft] = (f32x4){0.f, 0.f, 0.f, 0.f};
#pragma unroll
        for (int cc = 0; cc < 4; ++cc)
#pragma unroll
            for (int ft = 0; ft < 4; ++ft) {
                bf16x8 wf = *(const bf16x8*)&W[(ft * 16 + l16) * C + cc * 32 + quad * 8];
                acc[ft] = __builtin_amdgcn_mfma_f32_16x16x32_bf16(a[cc], wf, acc[ft], 0, 0, 0);
            }
        const int nr0 = n0 + wave * 16 + quad * 4;
#pragma unroll
        for (int ft = 0; ft < 4; ++ft) {
            const int f = ft * 16 + l16;
            const float bv = b3[f];
            bf16x4 o;
#pragma unroll
            for (int r = 0; r < 4; ++r) o[r] = (__bf16)(acc[ft][r] + bv);
            *(bf16x4*)&Gw[((size_t)t * F + f) * (size_t)N + nr0] = o;
        }
    }
}

// ---------------------------------------------------------------------------
// Kernel 2: O[t][f][q] += sum_key relu(Q[q]·K[key]) * G[key][f]
//
// v7 = R8-verified body + PREFETCH DEPTH 2. Two register tile-pairs (A,B);
// tile kb's staging write waits on loads issued TWO iterations earlier
// (~1000 cy aged -> latency covered); tile kb+2's loads issue right after
// the staging barrier. Plain register loads are not drained by s_barrier,
// so they stay in flight across both barriers. Loop unrolled by 2 for
// static register assignment (16 iters, even). Everything else identical:
// 512 threads (8 waves x 32 q), 32x32x16 MFMA, in-register S via
// relu+pack+v_permlane32_swap, KSPLIT=4, bank conflicts 0.
// ---------------------------------------------------------------------------
#define ATTN_COMPUTE                                                          \
    {                                                                         \
        bf16x8 ps[4];                                                         \
        _Pragma("unroll")                                                     \
        for (int kt = 0; kt < 2; ++kt) {                                      \
            f32x16 s;                                                         \
            _Pragma("unroll")                                                 \
            for (int r = 0; r < 16; ++r) s[r] = 0.f;                          \
            __builtin_amdgcn_s_setprio(1);                                    \
            _Pragma("unroll")                                                 \
            for (int fc = 0; fc < 4; ++fc) {                                  \
                bf16x8 kf = *(const bf16x8*)&Kt[(kt * 32 + m32) * KS + fc * 16 + hi * 8]; \
                s = __builtin_amdgcn_mfma_f32_32x32x16_bf16(kf, qf[fc], s, 0, 0, 0); \
            }                                                                 \
            __builtin_amdgcn_s_setprio(0);                                    \
            unsigned P[8];                                                    \
            _Pragma("unroll")                                                 \
            for (int m = 0; m < 8; ++m) {                                     \
                union { bf16x2 h; unsigned u; } pk;                           \
                pk.h[0] = (__bf16)fmaxf(s[2 * m], 0.f);                       \
                pk.h[1] = (__bf16)fmaxf(s[2 * m + 1], 0.f);                   \
                P[m] = pk.u;                                                  \
            }                                                                 \
            asm("v_permlane32_swap_b32 %0, %1" : "+v"(P[0]), "+v"(P[2]));     \
            asm("v_permlane32_swap_b32 %0, %1" : "+v"(P[1]), "+v"(P[3]));     \
            asm("v_permlane32_swap_b32 %0, %1" : "+v"(P[4]), "+v"(P[6]));     \
            asm("v_permlane32_swap_b32 %0, %1" : "+v"(P[5]), "+v"(P[7]));     \
            union { unsigned u[4]; bf16x8 v; } lo_, hi_;                      \
            lo_.u[0] = P[0]; lo_.u[1] = P[1]; lo_.u[2] = P[2]; lo_.u[3] = P[3]; \
            hi_.u[0] = P[4]; hi_.u[1] = P[5]; hi_.u[2] = P[6]; hi_.u[3] = P[7]; \
            ps[kt * 2]     = lo_.v;                                           \
            ps[kt * 2 + 1] = hi_.v;                                           \
        }                                                                     \
        __builtin_amdgcn_s_setprio(1);                                        \
        _Pragma("unroll")                                                     \
        for (int ft = 0; ft < 2; ++ft)                                        \
            _Pragma("unroll")                                                 \
            for (int kt = 0; kt < 2; ++kt)                                    \
                _Pragma("unroll")                                             \
                for (int kc = 0; kc < 2; ++kc) {                              \
                    bf16x8 gfr = *(const bf16x8*)&Gt[(ft * 32 + m32) * KS +   \
                                                     kt * 32 + kc * 16 + hi * 8]; \
                    oacc[ft] = __builtin_amdgcn_mfma_f32_32x32x16_bf16(       \
                        gfr, ps[kt * 2 + kc], oacc[ft], 0, 0, 0);             \
                }                                                             \
        __builtin_amdgcn_s_setprio(0);                                        \
    }

#define ATTN_TILE(KV, GV, KB2)                                                \
    {                                                                         \
        __syncthreads();                                                      \
        *(bf16x8*)&Kt[r8 * KS + c8] = KV;                                     \
        *(bf16x8*)&Gt[r8 * KS + c8] = GV;                                     \
        __syncthreads();                                                      \
        if ((KB2) < kb_hi) {                                                  \
            const int k0_ = (KB2) * 64;                                       \
            KV = *(const bf16x8*)&Kb[((size_t)t * N + k0_ + r8) * F + c8];    \
            GV = *(const bf16x8*)&Gw[((size_t)t * F + r8) * (size_t)N + k0_ + c8]; \
        }                                                                     \
        ATTN_COMPUTE                                                          \
    }

__global__ __launch_bounds__(512, 4) void attn_kernel(
    const __bf16* __restrict__ Qb, const __bf16* __restrict__ Kb,
    const __bf16* __restrict__ Gw, float* __restrict__ out)
{
    const int ks = blockIdx.x & (KSPLIT - 1);
    const int qb = (blockIdx.x / KSPLIT) & 15;   // N/256 = 16 q-blocks
    const int t  = blockIdx.x / (KSPLIT * 16);
    const int q0 = qb * 256;

    __shared__ __bf16 Kt[64 * KS];      // K tile [key][f]
    __shared__ __bf16 Gt[64 * KS];      // G tile [f][key]

    const int tid = threadIdx.x, wave = tid >> 6, lane = tid & 63;
    const int m32 = lane & 31, hi = lane >> 5;

    // Q B-frags (32x32x16): lane holds Q[q = q0+wave*32+m32][f = fc*16+hi*8+j]
    bf16x8 qf[4];
    {
        const __bf16* qrow = &Qb[((size_t)t * N + q0 + wave * 32 + m32) * F + hi * 8];
#pragma unroll
        for (int fc = 0; fc < 4; ++fc)
            qf[fc] = *(const bf16x8*)(qrow + fc * 16);
    }

    f32x16 oacc[2];   // D: col=q=m32, row=f=ft*32+(r&3)+8*(r>>2)+4*hi
#pragma unroll
    for (int ft = 0; ft < 2; ++ft)
#pragma unroll
        for (int r = 0; r < 16; ++r) oacc[ft][r] = 0.f;

    const int kb_lo = ks * (N / 64 / KSPLIT);
    const int kb_hi = kb_lo + (N / 64 / KSPLIT);   // 16 iterations (even)

    // staging unit: 512 threads cover 64x64 bf16 exactly once per tile
    const int r8 = tid >> 3, c8 = (tid & 7) * 8;

    // prologue: prefetch tiles kb_lo (A) and kb_lo+1 (B)
    bf16x8 kvA, gvA, kvB, gvB;
    {
        const int k0 = kb_lo * 64;
        kvA = *(const bf16x8*)&Kb[((size_t)t * N + k0 + r8) * F + c8];
        gvA = *(const bf16x8*)&Gw[((size_t)t * F + r8) * (size_t)N + k0 + c8];
        const int k1 = k0 + 64;
        kvB = *(const bf16x8*)&Kb[((size_t)t * N + k1 + r8) * F + c8];
        gvB = *(const bf16x8*)&Gw[((size_t)t * F + r8) * (size_t)N + k1 + c8];
    }

    for (int kb = kb_lo; kb < kb_hi; kb += 2) {
        ATTN_TILE(kvA, gvA, kb + 2)
        ATTN_TILE(kvB, gvB, kb + 3)
    }

    // Epilogue: f = ft*32+(r&3)+8*(r>>2)+4*hi, q = q0+wave*32+m32
    const int q = q0 + wave * 32 + m32;
#pragma unroll
    for (int ft = 0; ft < 2; ++ft)
#pragma unroll
        for (int r = 0; r < 16; ++r) {
            int f = ft * 32 + (r & 3) + 8 * (r >> 2) + 4 * hi;
            unsafeAtomicAdd(&out[((size_t)t * F + f) * (size_t)N + q], oacc[ft][r]);
        }
}

// ---------------------------------------------------------------------------
extern "C" void kernel_launch(void* const* d_in, const int* in_sizes, int n_in,
                              void* d_out, int out_size, void* d_ws, size_t ws_size,
                              hipStream_t stream) {
    const float* x1 = (const float*)d_in[0];
    const float* x2 = (const float*)d_in[1];
    const float* W1 = (const float*)d_in[2];
    const float* b1 = (const float*)d_in[3];
    const float* W2 = (const float*)d_in[4];
    const float* b2 = (const float*)d_in[5];
    const float* W3 = (const float*)d_in[6];
    const float* b3 = (const float*)d_in[7];
    float* out = (float*)d_out;

    __bf16* Qb = (__bf16*)d_ws;
    __bf16* Kb = Qb + (size_t)T * N * F;
    __bf16* Gw = Kb + (size_t)T * N * F;
    __bf16* Wb = Gw + (size_t)T * N * F;

    setup_kernel<<<dim3(3 * F * C / 256), dim3(256), 0, stream>>>(W1, W2, W3, Wb);
    proj_kernel<<<dim3(T * (N / 64), 3), dim3(256), 0, stream>>>(
        x1, x2, Wb, b1, b2, b3, Qb, Kb, Gw, out);
    attn_kernel<<<dim3(T * 16 * KSPLIT), dim3(512), 0, stream>>>(Qb, Kb, Gw, out);
}